// Round 1
// baseline (1135.715 us; speedup 1.0000x reference)
//
#include <hip/hip_runtime.h>

typedef __bf16 bf16_t;
typedef __bf16 bf16x8 __attribute__((ext_vector_type(8)));
typedef float  f32x4  __attribute__((ext_vector_type(4)));

#define HID    128
#define DIO    80
#define G4     512
#define TSTEP  512
#define BB     16
#define NBATCH 4096
#define NBLK   (NBATCH / BB)
#define HSTR   136  // LDS row stride (bf16 elems): 272B rows -> conflict-free b128 reads

// Pre-swizzled weight fragments (B-operand layout for mfma_f32_16x16x32_bf16):
// frag tile (ntile,kt) holds 512 bf16: elem[lane*8+j] = W[n=ntile*16+(lane&15)][k=kt*32+(lane>>4)*8+j]
__device__ bf16_t g_weff_frags[128 * 512];  // 32 gate ntiles x 4 ktiles
__device__ bf16_t g_whh_frags[128 * 512];   // same, for step 1
__device__ bf16_t g_wfc_frags[20 * 512];    // 5 y ntiles x 4 ktiles
__device__ float  g_weff[G4 * HID];
__device__ float  g_beff[G4];
__device__ float  g_b1[G4];

// W_eff = W_hh + W_ih @ W_fc ; b_eff = b_ih + b_hh + W_ih @ b_fc ; b1 = b_ih + b_hh
__global__ void k_weff(const float* __restrict__ W_ih, const float* __restrict__ W_hh,
                       const float* __restrict__ b_ih, const float* __restrict__ b_hh,
                       const float* __restrict__ W_fc, const float* __restrict__ b_fc) {
  int gid = blockIdx.x * blockDim.x + threadIdx.x;  // 65536 threads = 512*128
  int g = gid >> 7, k = gid & 127;
  float acc = W_hh[g * HID + k];
#pragma unroll 8
  for (int d = 0; d < DIO; ++d)
    acc = fmaf(W_ih[g * DIO + d], W_fc[d * HID + k], acc);
  g_weff[g * HID + k] = acc;
  if (k == 0) {
    float bb = b_ih[g] + b_hh[g];
    g_b1[g] = bb;
    float be = bb;
    for (int d = 0; d < DIO; ++d) be = fmaf(W_ih[g * DIO + d], b_fc[d], be);
    g_beff[g] = be;
  }
}

// Swizzle weights into MFMA B-fragment order (bf16).
__global__ void k_frag(const float* __restrict__ W_hh, const float* __restrict__ W_fc) {
  int tile = blockIdx.x;  // 0..275
  int lane = threadIdx.x; // 64
  int c = lane & 15, q = lane >> 4;
  if (tile < 128) {
    int gtile = tile >> 2, kt = tile & 3;
    int n = gtile * 16 + c;
#pragma unroll
    for (int j = 0; j < 8; ++j)
      g_weff_frags[tile * 512 + lane * 8 + j] = (bf16_t)g_weff[n * HID + kt * 32 + q * 8 + j];
  } else if (tile < 256) {
    int t2 = tile - 128;
    int gtile = t2 >> 2, kt = t2 & 3;
    int n = gtile * 16 + c;
#pragma unroll
    for (int j = 0; j < 8; ++j)
      g_whh_frags[t2 * 512 + lane * 8 + j] = (bf16_t)W_hh[n * HID + kt * 32 + q * 8 + j];
  } else {
    int t2 = tile - 256;  // 0..19
    int yt = t2 >> 2, kt = t2 & 3;
    int n = yt * 16 + c;  // < 80, all valid (80 = 5*16)
#pragma unroll
    for (int j = 0; j < 8; ++j)
      g_wfc_frags[t2 * 512 + lane * 8 + j] = (bf16_t)W_fc[n * HID + kt * 32 + q * 8 + j];
  }
}

__device__ __forceinline__ float fsigm(float x) {
  return __builtin_amdgcn_rcpf(1.0f + __builtin_amdgcn_exp2f(x * -1.4426950408889634f));
}
__device__ __forceinline__ float ftanh(float x) {
  return 1.0f - 2.0f * __builtin_amdgcn_rcpf(1.0f + __builtin_amdgcn_exp2f(x * 2.8853900817779268f));
}

// 256 blocks x 256 threads (4 waves). Block owns 16 batch rows for all 512 steps.
// Wave w owns, for each gate G in {i,f,g,o}, hidden cols [w*32, w*32+32) -> LSTM update is in-register.
__global__ __launch_bounds__(256, 1) void k_lstm(const float* __restrict__ h0,
                                                 const float* __restrict__ b_fc,
                                                 float* __restrict__ out) {
  __shared__ __align__(16) bf16_t hbuf[2][BB * HSTR];
  const int tid = threadIdx.x;
  const int lane = tid & 63;
  const int w = tid >> 6;
  const int c = lane & 15, q = lane >> 4;
  const int b0 = blockIdx.x * BB;

  // stage h0 -> hbuf[0] (bf16)
  for (int i = tid; i < BB * HID; i += 256) {
    int r = i >> 7, k = i & 127;
    hbuf[0][r * HSTR + k] = (bf16_t)h0[(long)(b0 + r) * HID + k];
  }

  // W_fc fragments: wave w -> y-tile w; wave 0 also y-tile 4 (cols 64..79)
  bf16x8 Wy[2][4];
  f32x4  ybias[2];
  {
    float by = b_fc[w * 16 + c];
    ybias[0] = (f32x4){by, by, by, by};
#pragma unroll
    for (int kt = 0; kt < 4; ++kt)
      Wy[0][kt] = *(const bf16x8*)&g_wfc_frags[(w * 4 + kt) * 512 + lane * 8];
  }
  if (w == 0) {
    float by = b_fc[64 + c];
    ybias[1] = (f32x4){by, by, by, by};
#pragma unroll
    for (int kt = 0; kt < 4; ++kt)
      Wy[1][kt] = *(const bf16x8*)&g_wfc_frags[(16 + kt) * 512 + lane * 8];
  }

  bf16x8 Wg[4][2][4];  // [gate][sub-tile][ktile] — register-resident weights
  float  bias[4][2];
  auto load_wg = [&](const bf16_t* frags, const float* bsrc) {
#pragma unroll
    for (int G = 0; G < 4; ++G)
#pragma unroll
      for (int s = 0; s < 2; ++s) {
        int gtile = G * 8 + w * 2 + s;
        bias[G][s] = bsrc[gtile * 16 + c];
#pragma unroll
        for (int kt = 0; kt < 4; ++kt)
          Wg[G][s][kt] = *(const bf16x8*)&frags[(gtile * 4 + kt) * 512 + lane * 8];
      }
  };

  f32x4 cst[2] = {(f32x4){0, 0, 0, 0}, (f32x4){0, 0, 0, 0}};  // c state, fp32
  bf16x8 hf[4];  // A-fragments of current h

  __syncthreads();  // h0 staged
#pragma unroll
  for (int kt = 0; kt < 4; ++kt)
    hf[kt] = *(const bf16x8*)&hbuf[0][c * HSTR + kt * 32 + q * 8];

  float* outp = out + (long)(b0 + q * 4) * TSTEP * DIO + w * 16 + c;

  auto step = [&](int t) {
    // gates = h_{t-1} @ W^T + bias
    f32x4 acc[4][2];
#pragma unroll
    for (int G = 0; G < 4; ++G)
#pragma unroll
      for (int s = 0; s < 2; ++s)
        acc[G][s] = (f32x4){bias[G][s], bias[G][s], bias[G][s], bias[G][s]};
#pragma unroll
    for (int kt = 0; kt < 4; ++kt)
#pragma unroll
      for (int G = 0; G < 4; ++G)
#pragma unroll
        for (int s = 0; s < 2; ++s)
          acc[G][s] = __builtin_amdgcn_mfma_f32_16x16x32_bf16(hf[kt], Wg[G][s][kt], acc[G][s], 0, 0, 0);
    // LSTM elementwise (fp32), write h_t (bf16) to the other LDS buffer
    const int buf = t & 1;
#pragma unroll
    for (int s = 0; s < 2; ++s)
#pragma unroll
      for (int r = 0; r < 4; ++r) {
        float iv = fsigm(acc[0][s][r]);
        float fv = fsigm(acc[1][s][r]);
        float gv = ftanh(acc[2][s][r]);
        float ov = fsigm(acc[3][s][r]);
        float cn = fv * cst[s][r] + iv * gv;
        cst[s][r] = cn;
        hbuf[buf][(q * 4 + r) * HSTR + w * 32 + s * 16 + c] = (bf16_t)(ov * ftanh(cn));
      }
    __syncthreads();  // single barrier per step (double-buffered h)
#pragma unroll
    for (int kt = 0; kt < 4; ++kt)
      hf[kt] = *(const bf16x8*)&hbuf[buf][c * HSTR + kt * 32 + q * 8];
    // y_t = h_t @ W_fc^T + b_fc  -> global (fp32)
    f32x4 ya = ybias[0];
#pragma unroll
    for (int kt = 0; kt < 4; ++kt)
      ya = __builtin_amdgcn_mfma_f32_16x16x32_bf16(hf[kt], Wy[0][kt], ya, 0, 0, 0);
#pragma unroll
    for (int r = 0; r < 4; ++r)
      outp[(long)r * TSTEP * DIO + (long)(t - 1) * DIO] = ya[r];
    if (w == 0) {
      f32x4 yb = ybias[1];
#pragma unroll
      for (int kt = 0; kt < 4; ++kt)
        yb = __builtin_amdgcn_mfma_f32_16x16x32_bf16(hf[kt], Wy[1][kt], yb, 0, 0, 0);
#pragma unroll
      for (int r = 0; r < 4; ++r)
        outp[(long)r * TSTEP * DIO + (long)(t - 1) * DIO + 64] = yb[r];
    }
  };

  // step 1: x0 == 0  =>  gates = h0 @ W_hh^T + (b_ih + b_hh)
  load_wg(g_whh_frags, g_b1);
  step(1);
  // steps 2..512: fused recurrence with W_eff / b_eff
  load_wg(g_weff_frags, g_beff);
  for (int t = 2; t <= TSTEP; ++t) step(t);
}

extern "C" void kernel_launch(void* const* d_in, const int* in_sizes, int n_in,
                              void* d_out, int out_size, void* d_ws, size_t ws_size,
                              hipStream_t stream) {
  const float* h0   = (const float*)d_in[0];
  const float* W_ih = (const float*)d_in[1];
  const float* W_hh = (const float*)d_in[2];
  const float* b_ih = (const float*)d_in[3];
  const float* b_hh = (const float*)d_in[4];
  const float* W_fc = (const float*)d_in[5];
  const float* b_fc = (const float*)d_in[6];
  float* out = (float*)d_out;

  k_weff<<<256, 256, 0, stream>>>(W_ih, W_hh, b_ih, b_hh, W_fc, b_fc);
  k_frag<<<276, 64, 0, stream>>>(W_hh, W_fc);
  k_lstm<<<NBLK, 256, 0, stream>>>(h0, b_fc, out);
}

// Round 2
// 1003.596 us; speedup vs baseline: 1.1316x; 1.1316x over previous
//
#include <hip/hip_runtime.h>

typedef __bf16 bf16_t;
typedef __bf16 bf16x4 __attribute__((ext_vector_type(4)));
typedef __bf16 bf16x8 __attribute__((ext_vector_type(8)));
typedef float  f32x4  __attribute__((ext_vector_type(4)));

#define HID    128
#define DIO    80
#define G4     512
#define TSTEP  512
#define BB     16
#define NBATCH 4096
#define NBLK   (NBATCH / BB)
#define HSTR   136  // LDS row stride (bf16 elems)

// Fragment layout (identical indexing for A- and B-operand of 16x16x32 bf16):
// frag tile (ntile,kt): elem[lane*8+j] = W[n=ntile*16+(lane&15)][k=kt*32+(lane>>4)*8+j]
__device__ bf16_t g_weff_frags[128 * 512];
__device__ bf16_t g_whh_frags[128 * 512];
__device__ bf16_t g_wfc_frags[20 * 512];
__device__ float  g_weff[G4 * HID];
__device__ float  g_beff[G4];
__device__ float  g_b1[G4];

// W_eff = W_hh + W_ih @ W_fc ; b_eff = b_ih + b_hh + W_ih @ b_fc ; b1 = b_ih + b_hh
__global__ void k_weff(const float* __restrict__ W_ih, const float* __restrict__ W_hh,
                       const float* __restrict__ b_ih, const float* __restrict__ b_hh,
                       const float* __restrict__ W_fc, const float* __restrict__ b_fc) {
  int gid = blockIdx.x * blockDim.x + threadIdx.x;
  int g = gid >> 7, k = gid & 127;
  float acc = W_hh[g * HID + k];
#pragma unroll 8
  for (int d = 0; d < DIO; ++d)
    acc = fmaf(W_ih[g * DIO + d], W_fc[d * HID + k], acc);
  g_weff[g * HID + k] = acc;
  if (k == 0) {
    float bb = b_ih[g] + b_hh[g];
    g_b1[g] = bb;
    float be = bb;
    for (int d = 0; d < DIO; ++d) be = fmaf(W_ih[g * DIO + d], b_fc[d], be);
    g_beff[g] = be;
  }
}

__global__ void k_frag(const float* __restrict__ W_hh, const float* __restrict__ W_fc) {
  int tile = blockIdx.x;  // 0..275
  int lane = threadIdx.x;
  int c = lane & 15, q = lane >> 4;
  if (tile < 128) {
    int gtile = tile >> 2, kt = tile & 3;
    int n = gtile * 16 + c;
#pragma unroll
    for (int j = 0; j < 8; ++j)
      g_weff_frags[tile * 512 + lane * 8 + j] = (bf16_t)g_weff[n * HID + kt * 32 + q * 8 + j];
  } else if (tile < 256) {
    int t2 = tile - 128;
    int gtile = t2 >> 2, kt = t2 & 3;
    int n = gtile * 16 + c;
#pragma unroll
    for (int j = 0; j < 8; ++j)
      g_whh_frags[t2 * 512 + lane * 8 + j] = (bf16_t)W_hh[n * HID + kt * 32 + q * 8 + j];
  } else {
    int t2 = tile - 256;  // 0..19
    int yt = t2 >> 2, kt = t2 & 3;
    int n = yt * 16 + c;
#pragma unroll
    for (int j = 0; j < 8; ++j)
      g_wfc_frags[t2 * 512 + lane * 8 + j] = (bf16_t)W_fc[n * HID + kt * 32 + q * 8 + j];
  }
}

__device__ __forceinline__ float fsigm(float x) {
  return __builtin_amdgcn_rcpf(1.0f + __builtin_amdgcn_exp2f(x * -1.4426950408889634f));
}
__device__ __forceinline__ float ftanh(float x) {
  return 1.0f - 2.0f * __builtin_amdgcn_rcpf(1.0f + __builtin_amdgcn_exp2f(x * 2.8853900817779268f));
}

// 256 blocks x 512 threads (8 waves -> 2 waves/SIMD). Block owns 16 batch rows for all 512 steps.
// Transposed MFMA: gates^T = W_tile(A) x h^T(B). Wave w owns hidden cols [w*16, w*16+16) of each gate.
// C-layout: col(lane&15)=batch row, row(q*4+r)=hidden unit -> LSTM update in-register,
// h writeback = one ds_write_b64, y store = one global_store_dwordx4.
__global__ __launch_bounds__(512, 2) void k_lstm(const float* __restrict__ h0,
                                                 const float* __restrict__ b_fc,
                                                 float* __restrict__ out) {
  __shared__ __align__(16) bf16_t hbuf[2][BB * HSTR];
  const int tid = threadIdx.x;
  const int lane = tid & 63;
  const int w = tid >> 6;  // 0..7
  const int c = lane & 15, q = lane >> 4;
  const int b0 = blockIdx.x * BB;

  // stage h0 -> hbuf[0]
  for (int i = tid; i < BB * HID; i += 512) {
    int r = i >> 7, k = i & 127;
    hbuf[0][r * HSTR + k] = (bf16_t)h0[(long)(b0 + r) * HID + k];
  }

  // W_fc A-fragments: waves 0..4 own y-tile w (dio cols w*16..w*16+16)
  bf16x8 Wy[4];
  f32x4  ybias;
  if (w < 5) {
#pragma unroll
    for (int kt = 0; kt < 4; ++kt)
      Wy[kt] = *(const bf16x8*)&g_wfc_frags[(w * 4 + kt) * 512 + lane * 8];
#pragma unroll
    for (int r = 0; r < 4; ++r) ybias[r] = b_fc[w * 16 + q * 4 + r];
  }

  bf16x8 Wg[4][4];  // [gate][ktile] — 64 VGPRs, register-resident
  f32x4  bias[4];   // per-r (hidden-unit) bias
  auto load_wg = [&](const bf16_t* frags, const float* bsrc) {
#pragma unroll
    for (int G = 0; G < 4; ++G) {
      int gtile = G * 8 + w;
#pragma unroll
      for (int r = 0; r < 4; ++r) bias[G][r] = bsrc[gtile * 16 + q * 4 + r];
#pragma unroll
      for (int kt = 0; kt < 4; ++kt)
        Wg[G][kt] = *(const bf16x8*)&frags[(gtile * 4 + kt) * 512 + lane * 8];
    }
  };

  f32x4 cst = (f32x4){0, 0, 0, 0};  // c state (fp32): units w*16+q*4+r, batch row c
  bf16x8 hf[4];                     // B-fragments of current h (h^T)

  __syncthreads();
#pragma unroll
  for (int kt = 0; kt < 4; ++kt)
    hf[kt] = *(const bf16x8*)&hbuf[0][c * HSTR + kt * 32 + q * 8];

  float* outp = out + (long)(b0 + c) * TSTEP * DIO + w * 16 + q * 4;

  auto step = [&](int t) {
    f32x4 acc[4];
#pragma unroll
    for (int G = 0; G < 4; ++G) acc[G] = bias[G];
#pragma unroll
    for (int kt = 0; kt < 4; ++kt)
#pragma unroll
      for (int G = 0; G < 4; ++G)
        acc[G] = __builtin_amdgcn_mfma_f32_16x16x32_bf16(Wg[G][kt], hf[kt], acc[G], 0, 0, 0);

    const int buf = t & 1;
    bf16x4 hv;
#pragma unroll
    for (int r = 0; r < 4; ++r) {
      float iv = fsigm(acc[0][r]);
      float fv = fsigm(acc[1][r]);
      float gv = ftanh(acc[2][r]);
      float ov = fsigm(acc[3][r]);
      float cn = fv * cst[r] + iv * gv;
      cst[r] = cn;
      hv[r] = (bf16_t)(ov * ftanh(cn));
    }
    *(bf16x4*)&hbuf[buf][c * HSTR + w * 16 + q * 4] = hv;  // one ds_write_b64
    __syncthreads();  // single barrier per step (double-buffered h)
#pragma unroll
    for (int kt = 0; kt < 4; ++kt)
      hf[kt] = *(const bf16x8*)&hbuf[buf][c * HSTR + kt * 32 + q * 8];

    if (w < 5) {  // wave-uniform branch
      f32x4 ya = ybias;
#pragma unroll
      for (int kt = 0; kt < 4; ++kt)
        ya = __builtin_amdgcn_mfma_f32_16x16x32_bf16(Wy[kt], hf[kt], ya, 0, 0, 0);
      *(f32x4*)&outp[(long)(t - 1) * DIO] = ya;  // one global_store_dwordx4
    }
  };

  // step 1: x0 == 0 => gates = h0 @ W_hh^T + (b_ih + b_hh)
  load_wg(g_whh_frags, g_b1);
  step(1);
  // steps 2..512: fused recurrence (x eliminated: W_eff = W_hh + W_ih@W_fc)
  load_wg(g_weff_frags, g_beff);
  for (int t = 2; t <= TSTEP; ++t) step(t);
}

extern "C" void kernel_launch(void* const* d_in, const int* in_sizes, int n_in,
                              void* d_out, int out_size, void* d_ws, size_t ws_size,
                              hipStream_t stream) {
  const float* h0   = (const float*)d_in[0];
  const float* W_ih = (const float*)d_in[1];
  const float* W_hh = (const float*)d_in[2];
  const float* b_ih = (const float*)d_in[3];
  const float* b_hh = (const float*)d_in[4];
  const float* W_fc = (const float*)d_in[5];
  const float* b_fc = (const float*)d_in[6];
  float* out = (float*)d_out;

  k_weff<<<256, 256, 0, stream>>>(W_ih, W_hh, b_ih, b_hh, W_fc, b_fc);
  k_frag<<<276, 64, 0, stream>>>(W_hh, W_fc);
  k_lstm<<<NBLK, 512, 0, stream>>>(h0, b_fc, out);
}